// Round 12
// baseline (132.130 us; speedup 1.0000x reference)
//
#include <hip/hip_runtime.h>
#include <hip/hip_bf16.h>

// ---------------------------------------------------------------------------
// HiddenEdgeDistanceMLP on MI355X (gfx950)
//
// reference:  s = s_lig[l] + s_poc[p]          [E,256]
//             h1 = silu(s @ W1.T + b1)         [E,128]
//             h2 = silu(h1 @ W2.T + b2)        [E,64]
//             out = relu(h2 @ W3.T + b3)       [E]
//
// v24 (R11): POCKET PROJECTION FUSED INTO EDGE.
//   Insight: pocket-Z rows (20480 = 83% of proj's work, 21 MB of HBM
//   round-trip) have ZERO reuse — each is consumed by exactly one edge
//   block. Only ligand-Z (x10 reuse) and weights deserve a precompute pass.
//   - edge block computes its 16 pocket rows in-block: A = s_poc rows via
//     the proven pack_split hi/lo path, B = pre-converted frag-ordered
//     bf16 W1F (64 KB workspace, x -log2e, L2-hot), 16 MFMA/wave on the
//     ~91%-idle MFMA pipe, D written straight into the zp LDS tile.
//     BITWISE identical arithmetic to the old proj (same pack_split, same
//     hi-then-lo per-ks MFMA order, scaled-then-RNE weights, no bias on
//     pocket rows). This is R0's fusion done right: zero redundancy.
//   - proj shrinks 6x: 128 ligand blocks + 4 W1F-convert + 1 W2F-convert.
//   Expected: proj 14 -> ~5us, edge ~flat, absmax exactly 0.001953125.
// v23 mechanisms kept: Z pre-scaled x(-log2e), W2F pre-converted, 512-thr
//   edge blocks (8 waves, 4 atoms each, single pass), swapped D^T MFMA
//   epilogue (fma dot + 2 shfl_xor, 64B stores), exp2 silu everywhere,
//   RNE cvt_pk packing, block=(b,jt) grid 1280, one barrier.
// ---------------------------------------------------------------------------

#define B_CPLX   128
#define NLB      32
#define NPB      160
#define SDIM     256
#define H1DIM    128
#define NL_TOT   (B_CPLX * NLB)         // 4096
#define NP_TOT   (B_CPLX * NPB)         // 20480
#define NROWS    (NL_TOT + NP_TOT)      // 24576
#define E_TOT    (B_CPLX * NLB * NPB)   // 655360

#define W1_LDS_STRIDE 264               // 256 + 8 bf16 pad
#define JT_CHUNK 16                     // pocket rows per block
#define ZP_STRIDE 132                   // 128 + 4 f32 pad (bank spread)

#define EDGE_BLOCKS (B_CPLX * 10)       // 1280 = (b, jt)

#define LIG_BLOCKS  128                 // ligand proj: 64 rows/block x 2 halves
#define W1F_BLOCKS  4                   // W1F converter blocks (1024 slots each)
#define PROJ_BLOCKS (LIG_BLOCKS + W1F_BLOCKS + 1)   // +1 = W2F block

#define NEG_LOG2E -1.4426950408889634f  // -log2(e)
#define NEG_LN2   -0.69314718055994531f // -ln(2)

typedef __bf16 bf16x8 __attribute__((ext_vector_type(8)));
typedef __bf16 bf16x2 __attribute__((ext_vector_type(2)));
typedef unsigned short ushortx8 __attribute__((ext_vector_type(8)));
typedef unsigned uintx4 __attribute__((ext_vector_type(4)));
typedef unsigned uintx2 __attribute__((ext_vector_type(2)));
typedef float f32x4 __attribute__((ext_vector_type(4)));
typedef float f32x2 __attribute__((ext_vector_type(2)));

#if __has_builtin(__builtin_amdgcn_exp2f)
#define EXP2F(x) __builtin_amdgcn_exp2f(x)
#else
#define EXP2F(x) exp2f(x)
#endif

// v_perm_b32: pack hi16(x0) low, hi16(x1) high (1 op)
__device__ __forceinline__ unsigned perm_hi16u(unsigned u0, unsigned u1) {
    return __builtin_amdgcn_perm(u1, u0, 0x07060302u);
}

// RNE pair-convert via HW v_cvt_pk_bf16_f32 -> packed u32
__device__ __forceinline__ unsigned cvt2_rne(float x0, float x1) {
    f32x2 p = {x0, x1};
    bf16x2 b = __builtin_convertvector(p, bf16x2);
    return __builtin_bit_cast(unsigned, b);
}

// f32x4 -> 4 bf16 (RNE, 2 cvt_pk ops)
__device__ __forceinline__ uintx2 pack4_rne_u(f32x4 v) {
    uintx2 r;
    r[0] = cvt2_rne(v[0], v[1]);
    r[1] = cvt2_rne(v[2], v[3]);
    return r;
}

// RNE pack of 8 floats via cvt_pk
__device__ __forceinline__ bf16x8 pack8_rne(const float* x) {
    uintx4 h;
#pragma unroll
    for (int j = 0; j < 4; ++j) h[j] = cvt2_rne(x[2 * j], x[2 * j + 1]);
    return __builtin_bit_cast(bf16x8, h);
}

// hi/lo split (proj path): hi = trunc bf16 (perm), lo = RNE bf16(x - hi)
__device__ __forceinline__ void pack_split(const float* x, bf16x8& hi, bf16x8& lo) {
    uintx4 h, l;
#pragma unroll
    for (int j = 0; j < 4; ++j) {
        float x0 = x[2 * j], x1 = x[2 * j + 1];
        unsigned u0 = __builtin_bit_cast(unsigned, x0);
        unsigned u1 = __builtin_bit_cast(unsigned, x1);
        h[j] = perm_hi16u(u0, u1);
        float hf0 = __builtin_bit_cast(float, u0 & 0xFFFF0000u);
        float hf1 = __builtin_bit_cast(float, u1 & 0xFFFF0000u);
        l[j] = cvt2_rne(x0 - hf0, x1 - hf1);
    }
    hi = __builtin_bit_cast(bf16x8, h);
    lo = __builtin_bit_cast(bf16x8, l);
}

// pre-scaled silu: t = -log2e * s  ->  u = t * sigma(s) = -log2e * silu(s)
__device__ __forceinline__ float silu_u(float t) {
    float e = EXP2F(t);
    float r = __builtin_amdgcn_rcpf(1.0f + e);
    return t * r;
}

// ---------------------------------------------------------------------------
// Kernel 1 (proj, 133 blocks):
//   bid < 128: ligand Z rows only (64 rows x 128 cols per block, hi/lo MFMA,
//              b1 folded, Z pre-scaled x -log2e).
//   bid 128..131: convert W1F = frag-ordered bf16 of W1 x(-log2e), 1024
//              slots each; frag(chunk=nblk*8+ks, lane) =
//              W1'[n=nblk*16+(lane&15)][ks*32+(lane>>4)*8 ..+8].
//   bid 132:   convert W2F (frag-ordered bf16 W2, unscaled).
// ---------------------------------------------------------------------------
__global__ __launch_bounds__(256) void proj_kernel(
    const float* __restrict__ s_lig, const float* __restrict__ W1,
    const float* __restrict__ b1,    const float* __restrict__ W2,
    float* __restrict__ Z,           unsigned short* __restrict__ W2F,
    unsigned short* __restrict__ W1F)
{
    const int bid = blockIdx.x;
    const int tid = threadIdx.x;

    if (bid >= LIG_BLOCKS) {
        const int u = bid - LIG_BLOCKS;
        if (u < W1F_BLOCKS) {
            // W1F quarter u: slots u*1024 + tid + s*256  (4096 slots total)
#pragma unroll
            for (int s = 0; s < 4; ++s) {
                const int slot   = u * 1024 + tid + s * 256;
                const int lane_s = slot & 63;
                const int chunk  = slot >> 6;             // 0..63
                const int nblk   = chunk >> 3;            // 0..7
                const int ks     = chunk & 7;             // 0..7
                const int n      = nblk * 16 + (lane_s & 15);
                const int k0     = ks * 32 + (lane_s >> 4) * 8;
                const float* wsrc = W1 + (size_t)n * SDIM + k0;
                f32x4 wa = *(const f32x4*)wsrc * NEG_LOG2E;
                f32x4 wb = *(const f32x4*)(wsrc + 4) * NEG_LOG2E;
                uintx4 us;
                us[0] = cvt2_rne(wa[0], wa[1]);
                us[1] = cvt2_rne(wa[2], wa[3]);
                us[2] = cvt2_rne(wb[0], wb[1]);
                us[3] = cvt2_rne(wb[2], wb[3]);
                *(uintx4*)(&W1F[slot * 8]) = us;
            }
        } else {
            // W2F: 1024 slots, 4 per thread (unscaled RNE bf16)
#pragma unroll
            for (int s = 0; s < 4; ++s) {
                const int slot   = tid + s * 256;
                const int lane_s = slot & 63;
                const int chunk  = slot >> 6;
                const int nt     = chunk >> 2;
                const int ks     = chunk & 3;
                const int n      = nt * 16 + (lane_s & 15);
                const int k0     = ks * 32 + (lane_s >> 4) * 8;
                const float* wsrc = W2 + (size_t)n * H1DIM + k0;
                f32x4 wa = *(const f32x4*)wsrc;
                f32x4 wb = *(const f32x4*)(wsrc + 4);
                uintx4 us;
                us[0] = cvt2_rne(wa[0], wa[1]);
                us[1] = cvt2_rne(wa[2], wa[3]);
                us[2] = cvt2_rne(wb[0], wb[1]);
                us[3] = cvt2_rne(wb[2], wb[3]);
                *(uintx4*)(&W2F[slot * 8]) = us;
            }
        }
        return;
    }

    // ---- ligand projection (rows 0..4095 only) ----
    __shared__ unsigned short w1s[64 * W1_LDS_STRIDE];   // 33.8 KB

    const int tg   = bid >> 1;                    // row-tile group 0..63
    const int half = bid & 1;                     // N half

    {
        const f32x4* w4 = (const f32x4*)(W1 + (size_t)half * 64 * SDIM);  // 4096 units
#pragma unroll
        for (int r = 0; r < 2; ++r) {
            f32x4 t[8];
#pragma unroll
            for (int s = 0; s < 8; ++s) t[s] = w4[tid + (r * 8 + s) * 256];
#pragma unroll
            for (int s = 0; s < 8; ++s) {
                const int u = tid + (r * 8 + s) * 256;
                const int n = u >> 6;             // 64 f32x4 per 256-col row
                const int k4 = u & 63;
                uintx2 us = pack4_rne_u(t[s] * NEG_LOG2E);   // 2 cvt_pk + 1 pk-mul
                *(uintx2*)(&w1s[n * W1_LDS_STRIDE + k4 * 4]) = us;
            }
        }
    }
    __syncthreads();

    const int lane = tid & 63;
    const int widx = tid >> 6;
    const int c    = lane & 15;
    const int q    = lane >> 4;
    const int tile = tg * 4 + widx;               // 0..255
    const int row  = tile * 16 + c;               // 0..4095 (ligand only)

    const float* src = s_lig + (size_t)row * SDIM;

    f32x4 acc[4];
#pragma unroll
    for (int nt = 0; nt < 4; ++nt) acc[nt] = (f32x4){0.f, 0.f, 0.f, 0.f};

#pragma unroll
    for (int ks = 0; ks < 8; ++ks) {              // K = 256 = 8 x 32
        const int k0 = ks * 32 + q * 8;
        f32x4 xa = *reinterpret_cast<const f32x4*>(src + k0);
        f32x4 xb = *reinterpret_cast<const f32x4*>(src + k0 + 4);
        float xv[8] = {xa[0], xa[1], xa[2], xa[3], xb[0], xb[1], xb[2], xb[3]};
        bf16x8 ahi, alo;
        pack_split(xv, ahi, alo);
        bf16x8 bfrag[4];
#pragma unroll
        for (int nt = 0; nt < 4; ++nt)
            bfrag[nt] = *reinterpret_cast<const bf16x8*>(
                &w1s[(nt * 16 + c) * W1_LDS_STRIDE + k0]);
#pragma unroll
        for (int nt = 0; nt < 4; ++nt)            // hi pass (dep distance 4)
            acc[nt] = __builtin_amdgcn_mfma_f32_16x16x32_bf16(ahi, bfrag[nt], acc[nt], 0, 0, 0);
#pragma unroll
        for (int nt = 0; nt < 4; ++nt)            // lo pass
            acc[nt] = __builtin_amdgcn_mfma_f32_16x16x32_bf16(alo, bfrag[nt], acc[nt], 0, 0, 0);
    }

    // C/D layout: col n' = lane&15, row m = q*4 + reg; all rows are ligand
    const int mb = tile * 16 + q * 4;
#pragma unroll
    for (int nt = 0; nt < 4; ++nt) {
        const int n = half * 64 + nt * 16 + c;
        const float bias = b1[n] * NEG_LOG2E;     // scaled bias (Z pre-scaled)
#pragma unroll
        for (int r = 0; r < 4; ++r)
            Z[(size_t)(mb + r) * H1DIM + n] = acc[nt][r] + bias;
    }
}

// ---------------------------------------------------------------------------
// Kernel 2: block = (complex b, pocket chunk jt); 1280 blocks x 512 threads.
//   Pocket Z computed IN-BLOCK (A = s_poc hi/lo pack_split, B = W1F frags,
//   16 MFMA/wave) -> zp LDS. Ligand Z staged from workspace. One barrier.
//   Main loop + swapped D^T epilogue unchanged from v23.
// ---------------------------------------------------------------------------
__global__ __launch_bounds__(512) void edge_kernel(
    const float* __restrict__ Z,  const unsigned short* __restrict__ W2F,
    const unsigned short* __restrict__ W1F,
    const float* __restrict__ s_poc,
    const float* __restrict__ b2, const float* __restrict__ W3,
    const float* __restrict__ b3, float* __restrict__ out)
{
    __shared__ float zp[JT_CHUNK * ZP_STRIDE];            // 8.4 KB (computed)
    __shared__ float zl[NLB * H1DIM];                     // 16 KB (pre-scaled)
    __shared__ unsigned short w2s[16 * 64 * 8];           // 16 KB frag-ordered

    const int tid = threadIdx.x;                  // 0..511
    const int b   = blockIdx.x / 10;
    const int jt  = blockIdx.x - b * 10;          // 0..9

    const int lane = tid & 63;
    const int widx = tid >> 6;                    // 0..7
    const int c    = lane & 15;
    const int q    = lane >> 4;

    // stage W2 fragments: pure 16B copies from the precomputed region
    {
#pragma unroll
        for (int s = 0; s < 2; ++s) {
            const int slot = tid + s * 512;               // 0..1023
            *(ushortx8*)(&w2s[slot * 8]) = *(const ushortx8*)(&W2F[slot * 8]);
        }
    }

    // stage ALL 32 ligand rows (pre-scaled): pure copy, 2 f32x4 per thread
    {
        const float* zlg = Z + (size_t)(b * NLB) * H1DIM;
#pragma unroll
        for (int s = 0; s < 2; ++s) {
            const int u   = tid + s * 512;                // 0..1023
            const int row = u >> 5;
            const int c4  = u & 31;
            *(f32x4*)(&zl[row * H1DIM + c4 * 4]) =
                *(const f32x4*)(zlg + (size_t)row * H1DIM + c4 * 4);
        }
    }

    // ---- in-block pocket projection (bitwise = old proj, no bias) ----
    // A: lane c reads s_poc row (b*160 + jt*16 + c), k-slice q (pack_split).
    // B: W1F frag chunk = widx*8 + ks -> wave widx owns cols widx*16..+16.
    // D: lane holds zp[row = q*4+r][col = widx*16 + c].
    {
        const float* sp = s_poc + (size_t)(b * NPB + jt * JT_CHUNK + c) * SDIM;
        const unsigned short* wf = W1F + ((size_t)widx * 8 * 64 + lane) * 8;
        f32x4 pacc = (f32x4){0.f, 0.f, 0.f, 0.f};
#pragma unroll 2
        for (int ks = 0; ks < 8; ++ks) {          // K = 256 = 8 x 32
            const int k0 = ks * 32 + q * 8;
            f32x4 xa = *(const f32x4*)(sp + k0);
            f32x4 xb = *(const f32x4*)(sp + k0 + 4);
            float xv[8] = {xa[0], xa[1], xa[2], xa[3], xb[0], xb[1], xb[2], xb[3]};
            bf16x8 phi, plo;
            pack_split(xv, phi, plo);
            bf16x8 bfr = *(const bf16x8*)(wf + (size_t)ks * 64 * 8);
            pacc = __builtin_amdgcn_mfma_f32_16x16x32_bf16(phi, bfr, pacc, 0, 0, 0);
            pacc = __builtin_amdgcn_mfma_f32_16x16x32_bf16(plo, bfr, pacc, 0, 0, 0);
        }
#pragma unroll
        for (int r = 0; r < 4; ++r)
            zp[(q * 4 + r) * ZP_STRIDE + widx * 16 + c] = pacc[r];
    }

    // swapped-D layout: lane reg (nt, r) <-> h2 channel m = nt*16 + q*4 + r.
    // b2 scaled by -log2e (acc accumulates t2); W3 scaled by -ln2.
    f32x4 b2v[4], w3v[4];
#pragma unroll
    for (int nt = 0; nt < 4; ++nt) {
        f32x4 bv = *(const f32x4*)(b2 + nt * 16 + q * 4);
        f32x4 wv = *(const f32x4*)(W3 + nt * 16 + q * 4);
        b2v[nt] = bv * NEG_LOG2E;
        w3v[nt] = wv * NEG_LN2;
    }
    const float b3v = b3[0];

    __syncthreads();   // w2s + zl + zp (computed) visible; the ONLY barrier

    const float* prow = &zp[c * ZP_STRIDE];
    const unsigned short* wbase = &w2s[lane * 8];          // + chunk*512 ushorts

    // acc init = -log2e * b2 (per-channel, vectorized over r)
    f32x4 acc[4][4];                               // [atom][nt]
#pragma unroll
    for (int a = 0; a < 4; ++a)
#pragma unroll
        for (int nt = 0; nt < 4; ++nt) acc[a][nt] = b2v[nt];

    // wave's 4 atoms: widx*4 + a
    const float* lrow0 = &zl[(widx * 4) * H1DIM];

#pragma unroll
    for (int ks = 0; ks < 4; ++ks) {               // K = 128 = 4 x 32
        const int k0 = ks * 32 + q * 8;
        bf16x8 bfr[4];
#pragma unroll
        for (int nt = 0; nt < 4; ++nt)             // conflict-free ds_read_b128
            bfr[nt] = *(const bf16x8*)(wbase + (nt * 4 + ks) * 512);
        f32x4 pa = *(const f32x4*)(prow + k0);
        f32x4 pb = *(const f32x4*)(prow + k0 + 4);
#pragma unroll
        for (int a = 0; a < 4; ++a) {              // 4 atoms share bfr/pa/pb
            f32x4 la0 = *(const f32x4*)(lrow0 + a * H1DIM + k0);
            f32x4 la1 = *(const f32x4*)(lrow0 + a * H1DIM + k0 + 4);
            float hv[8];
#pragma unroll
            for (int j = 0; j < 4; ++j) {          // u = -log2e * silu(s)
                hv[j]     = silu_u(pa[j] + la0[j]);
                hv[4 + j] = silu_u(pb[j] + la1[j]);
            }
            bf16x8 af = pack8_rne(hv);
#pragma unroll
            for (int nt = 0; nt < 4; ++nt)         // SWAPPED: D^T, bitwise
                acc[a][nt] = __builtin_amdgcn_mfma_f32_16x16x32_bf16(bfr[nt], af, acc[a][nt], 0, 0, 0);
        }
    }

    // epilogue: lane holds t2 for channels m=nt*16+q*4+r, pocket c.
    // dot(silu_u(t2), w3v) per lane -> sum over q via shfl_xor 16/32.
#pragma unroll
    for (int at = 0; at < 4; ++at) {
        const f32x4* A = acc[at];
        float s0 = 0.f, s1 = 0.f, s2 = 0.f, s3 = 0.f;
#pragma unroll
        for (int nt = 0; nt < 4; ++nt) {           // u2 = -log2e*silu(h2pre)
            s0 += silu_u(A[nt][0]) * w3v[nt][0];
            s1 += silu_u(A[nt][1]) * w3v[nt][1];
            s2 += silu_u(A[nt][2]) * w3v[nt][2];
            s3 += silu_u(A[nt][3]) * w3v[nt][3];
        }
        float v = (s0 + s1) + (s2 + s3);           // per-lane partial (16 ch)
        v += __shfl_xor(v, 16);                    // q ^ 1
        v += __shfl_xor(v, 32);                    // q ^ 2 -> all 64 channels
        if (lane < 16) {
            const int e0 = (b * NLB + widx * 4 + at) * NPB + jt * JT_CHUNK;
            out[e0 + lane] = fmaxf(v + b3v, 0.0f); // 64B coalesced
        }
    }
}

// ---------------------------------------------------------------------------
extern "C" void kernel_launch(void* const* d_in, const int* in_sizes, int n_in,
                              void* d_out, int out_size, void* d_ws, size_t ws_size,
                              hipStream_t stream)
{
    const float* s_lig = (const float*)d_in[0];
    const float* s_poc = (const float*)d_in[1];
    const float* W1    = (const float*)d_in[4];
    const float* b1    = (const float*)d_in[5];
    const float* W2    = (const float*)d_in[6];
    const float* b2    = (const float*)d_in[7];
    const float* W3    = (const float*)d_in[8];
    const float* b3    = (const float*)d_in[9];

    float* Z = (float*)d_ws;                       // ligand Z (pre-scaled)
    unsigned short* W2F = (unsigned short*)(Z + (size_t)NROWS * H1DIM);  // 16 KB
    unsigned short* W1F = W2F + 1024 * 8;                                // 64 KB

    hipLaunchKernelGGL(proj_kernel, dim3(PROJ_BLOCKS), dim3(256), 0, stream,
                       s_lig, W1, b1, W2, Z, W2F, W1F);
    hipLaunchKernelGGL(edge_kernel, dim3(EDGE_BLOCKS), dim3(512), 0, stream,
                       Z, W2F, W1F, s_poc, b2, W3, b3, (float*)d_out);
}

// Round 13
// 126.485 us; speedup vs baseline: 1.0446x; 1.0446x over previous
//
#include <hip/hip_runtime.h>
#include <hip/hip_bf16.h>

// ---------------------------------------------------------------------------
// HiddenEdgeDistanceMLP on MI355X (gfx950)
//
// reference:  s = s_lig[l] + s_poc[p]          [E,256]
//             h1 = silu(s @ W1.T + b1)         [E,128]
//             h2 = silu(h1 @ W2.T + b2)        [E,64]
//             out = relu(h2 @ W3.T + b3)       [E]
//
// v25 (R12): REVERT to v23 (best, 126.4us) + single-bf16 POCKET projection.
//   R11 post-mortem: in-edge pocket proj regressed edge 36->57us (serial
//   16-MFMA chain pre-barrier + R6-style scattered s_poc reads). Fusion is
//   refuted; v23 structure restored verbatim (edge untouched).
//   This round's cut is proj-only: pocket rows (tile-groups 64..383 = 83%
//   of proj work) skip the hi/lo split — single RNE-bf16 A + 4 MFMA/ks
//   (was 8) and pack8_rne (~1.5 op/elem, was pack_split ~5). Ligand rows
//   (x10 reuse) keep the exact hi/lo path. Error analysis: |Z|~0.6 ->
//   single-bf16 pocket Z adds ~1.2e-3 to silu input t, same order as the
//   h1 rounding already present; expect absmax ~0.003 < 7.5e-3 threshold.
// v23 mechanisms kept EXACTLY: Z pre-scaled x(-log2e), W2F pre-converted
//   (block 0), 512-thr edge blocks (8 waves x 4 atoms, single pass),
//   swapped D^T MFMA epilogue (fma dot + 2 shfl_xor, 64B stores), exp2
//   silu everywhere, RNE cvt_pk packing, block=(b,jt) grid 1280, one
//   barrier, no min-waves bound.
// ---------------------------------------------------------------------------

#define B_CPLX   128
#define NLB      32
#define NPB      160
#define SDIM     256
#define H1DIM    128
#define NL_TOT   (B_CPLX * NLB)         // 4096
#define NP_TOT   (B_CPLX * NPB)         // 20480
#define NROWS    (NL_TOT + NP_TOT)      // 24576
#define E_TOT    (B_CPLX * NLB * NPB)   // 655360

#define W1_LDS_STRIDE 264               // 256 + 8 bf16 pad
#define JT_CHUNK 16                     // pocket rows per block
#define ZP_STRIDE 132                   // 128 + 4 f32 pad (bank spread)

#define EDGE_BLOCKS (B_CPLX * 10)       // 1280 = (b, jt)

#define LIG_TG 64                       // tile-groups 0..63 are ligand rows

#define NEG_LOG2E -1.4426950408889634f  // -log2(e)
#define NEG_LN2   -0.69314718055994531f // -ln(2)

typedef __bf16 bf16x8 __attribute__((ext_vector_type(8)));
typedef __bf16 bf16x2 __attribute__((ext_vector_type(2)));
typedef unsigned short ushortx8 __attribute__((ext_vector_type(8)));
typedef unsigned uintx4 __attribute__((ext_vector_type(4)));
typedef unsigned uintx2 __attribute__((ext_vector_type(2)));
typedef float f32x4 __attribute__((ext_vector_type(4)));
typedef float f32x2 __attribute__((ext_vector_type(2)));

#if __has_builtin(__builtin_amdgcn_exp2f)
#define EXP2F(x) __builtin_amdgcn_exp2f(x)
#else
#define EXP2F(x) exp2f(x)
#endif

// v_perm_b32: pack hi16(x0) low, hi16(x1) high (1 op)
__device__ __forceinline__ unsigned perm_hi16u(unsigned u0, unsigned u1) {
    return __builtin_amdgcn_perm(u1, u0, 0x07060302u);
}

// RNE pair-convert via HW v_cvt_pk_bf16_f32 -> packed u32
__device__ __forceinline__ unsigned cvt2_rne(float x0, float x1) {
    f32x2 p = {x0, x1};
    bf16x2 b = __builtin_convertvector(p, bf16x2);
    return __builtin_bit_cast(unsigned, b);
}

// f32x4 -> 4 bf16 (RNE, 2 cvt_pk ops), as uintx2 for a ds_write_b64
__device__ __forceinline__ uintx2 pack4_rne_u(f32x4 v) {
    uintx2 r;
    r[0] = cvt2_rne(v[0], v[1]);
    r[1] = cvt2_rne(v[2], v[3]);
    return r;
}

// RNE pack of 8 floats via cvt_pk (compiler-lowered, no inline asm)
__device__ __forceinline__ bf16x8 pack8_rne(const float* x) {
    uintx4 h;
#pragma unroll
    for (int j = 0; j < 4; ++j) h[j] = cvt2_rne(x[2 * j], x[2 * j + 1]);
    return __builtin_bit_cast(bf16x8, h);
}

// hi/lo split (ligand proj path): hi = trunc bf16 (perm), lo = RNE bf16(x-hi)
__device__ __forceinline__ void pack_split(const float* x, bf16x8& hi, bf16x8& lo) {
    uintx4 h, l;
#pragma unroll
    for (int j = 0; j < 4; ++j) {
        float x0 = x[2 * j], x1 = x[2 * j + 1];
        unsigned u0 = __builtin_bit_cast(unsigned, x0);
        unsigned u1 = __builtin_bit_cast(unsigned, x1);
        h[j] = perm_hi16u(u0, u1);
        float hf0 = __builtin_bit_cast(float, u0 & 0xFFFF0000u);
        float hf1 = __builtin_bit_cast(float, u1 & 0xFFFF0000u);
        l[j] = cvt2_rne(x0 - hf0, x1 - hf1);
    }
    hi = __builtin_bit_cast(bf16x8, h);
    lo = __builtin_bit_cast(bf16x8, l);
}

// pre-scaled silu: t = -log2e * s  ->  u = t * sigma(s) = -log2e * silu(s)
__device__ __forceinline__ float silu_u(float t) {
    float e = EXP2F(t);
    float r = __builtin_amdgcn_rcpf(1.0f + e);
    return t * r;
}

// ---------------------------------------------------------------------------
// Kernel 1: Z[m][n] = -log2e * (X[m] @ W1[n] (+ b1[n] if ligand row))
//   Ligand tile-groups (tg<64): hi/lo split, Z near-exact (x10 reuse).
//   Pocket tile-groups (tg>=64): SINGLE RNE-bf16 A, 4 MFMA/ks (new in v25).
//   Block 0 additionally writes the fragment-ordered bf16 W2 to workspace.
// ---------------------------------------------------------------------------
__global__ __launch_bounds__(256) void proj_kernel(
    const float* __restrict__ s_lig, const float* __restrict__ s_poc,
    const float* __restrict__ W1,    const float* __restrict__ b1,
    const float* __restrict__ W2,
    float* __restrict__ Z,           unsigned short* __restrict__ W2F)
{
    __shared__ unsigned short w1s[64 * W1_LDS_STRIDE];   // 33.8 KB

    const int tid  = threadIdx.x;
    const int tg   = blockIdx.x >> 1;             // row-tile group 0..383
    const int half = blockIdx.x & 1;              // N half
    const bool is_lig = (tg < LIG_TG);            // block-uniform

    // block 0 extra duty: frag-ordered bf16 W2 -> workspace (RNE)
    if (blockIdx.x == 0) {
#pragma unroll
        for (int s = 0; s < 4; ++s) {
            const int slot   = tid + s * 256;             // 0..1023
            const int lane_s = slot & 63;
            const int chunk  = slot >> 6;
            const int nt     = chunk >> 2;
            const int ks     = chunk & 3;
            const int n      = nt * 16 + (lane_s & 15);
            const int k0     = ks * 32 + (lane_s >> 4) * 8;
            const float* wsrc = W2 + (size_t)n * H1DIM + k0;
            f32x4 wa = *(const f32x4*)wsrc;
            f32x4 wb = *(const f32x4*)(wsrc + 4);
            uintx4 us;
            us[0] = cvt2_rne(wa[0], wa[1]);
            us[1] = cvt2_rne(wa[2], wa[3]);
            us[2] = cvt2_rne(wb[0], wb[1]);
            us[3] = cvt2_rne(wb[2], wb[3]);
            *(uintx4*)(&W2F[slot * 8]) = us;
        }
    }

    {
        const f32x4* w4 = (const f32x4*)(W1 + (size_t)half * 64 * SDIM);  // 4096 units
#pragma unroll
        for (int r = 0; r < 2; ++r) {
            f32x4 t[8];
#pragma unroll
            for (int s = 0; s < 8; ++s) t[s] = w4[tid + (r * 8 + s) * 256];
#pragma unroll
            for (int s = 0; s < 8; ++s) {
                const int u = tid + (r * 8 + s) * 256;
                const int n = u >> 6;             // 64 f32x4 per 256-col row
                const int k4 = u & 63;
                uintx2 us = pack4_rne_u(t[s] * NEG_LOG2E);   // 2 cvt_pk + 1 pk-mul
                *(uintx2*)(&w1s[n * W1_LDS_STRIDE + k4 * 4]) = us;
            }
        }
    }
    __syncthreads();

    const int lane = tid & 63;
    const int widx = tid >> 6;
    const int c    = lane & 15;
    const int q    = lane >> 4;
    const int tile = tg * 4 + widx;               // 0..1535
    const int row  = tile * 16 + c;

    const float* src = is_lig ? (s_lig + (size_t)row * SDIM)
                              : (s_poc + (size_t)(row - NL_TOT) * SDIM);

    f32x4 acc[4];
#pragma unroll
    for (int nt = 0; nt < 4; ++nt) acc[nt] = (f32x4){0.f, 0.f, 0.f, 0.f};

#pragma unroll
    for (int ks = 0; ks < 8; ++ks) {              // K = 256 = 8 x 32
        const int k0 = ks * 32 + q * 8;
        f32x4 xa = *reinterpret_cast<const f32x4*>(src + k0);
        f32x4 xb = *reinterpret_cast<const f32x4*>(src + k0 + 4);
        float xv[8] = {xa[0], xa[1], xa[2], xa[3], xb[0], xb[1], xb[2], xb[3]};
        bf16x8 bfrag[4];
#pragma unroll
        for (int nt = 0; nt < 4; ++nt)
            bfrag[nt] = *reinterpret_cast<const bf16x8*>(
                &w1s[(nt * 16 + c) * W1_LDS_STRIDE + k0]);
        if (is_lig) {                             // exact hi/lo path (x10 reuse)
            bf16x8 ahi, alo;
            pack_split(xv, ahi, alo);
#pragma unroll
            for (int nt = 0; nt < 4; ++nt)        // hi pass (dep distance 4)
                acc[nt] = __builtin_amdgcn_mfma_f32_16x16x32_bf16(ahi, bfrag[nt], acc[nt], 0, 0, 0);
#pragma unroll
            for (int nt = 0; nt < 4; ++nt)        // lo pass
                acc[nt] = __builtin_amdgcn_mfma_f32_16x16x32_bf16(alo, bfrag[nt], acc[nt], 0, 0, 0);
        } else {                                  // pocket: single RNE bf16
            bf16x8 af = pack8_rne(xv);
#pragma unroll
            for (int nt = 0; nt < 4; ++nt)
                acc[nt] = __builtin_amdgcn_mfma_f32_16x16x32_bf16(af, bfrag[nt], acc[nt], 0, 0, 0);
        }
    }

    // C/D layout: col n' = lane&15, row m = q*4 + reg
    const int mb = tile * 16 + q * 4;
#pragma unroll
    for (int nt = 0; nt < 4; ++nt) {
        const int n = half * 64 + nt * 16 + c;
        const float bias = is_lig ? (b1[n] * NEG_LOG2E) : 0.0f;  // b1 on ligand only
#pragma unroll
        for (int r = 0; r < 4; ++r)
            Z[(size_t)(mb + r) * H1DIM + n] = acc[nt][r] + bias;
    }
}

// ---------------------------------------------------------------------------
// Kernel 2 (VERBATIM v23): block = (complex b, pocket chunk jt); 1280 blocks
//   x 512 threads (8 waves). Wave widx owns atoms widx*4..+3, single pass.
//   Staging split over 8 waves; one barrier; SWAPPED D^T MFMA epilogue.
// ---------------------------------------------------------------------------
__global__ __launch_bounds__(512) void edge_kernel(
    const float* __restrict__ Z,  const unsigned short* __restrict__ W2F,
    const float* __restrict__ b2, const float* __restrict__ W3,
    const float* __restrict__ b3, float* __restrict__ out)
{
    __shared__ float zp[JT_CHUNK * ZP_STRIDE];            // 8.4 KB (pre-scaled)
    __shared__ float zl[NLB * H1DIM];                     // 16 KB (pre-scaled)
    __shared__ unsigned short w2s[16 * 64 * 8];           // 16 KB frag-ordered

    const int tid = threadIdx.x;                  // 0..511
    const int b   = blockIdx.x / 10;
    const int jt  = blockIdx.x - b * 10;          // 0..9

    // stage W2 fragments: pure 16B copies from the precomputed region
    {
#pragma unroll
        for (int s = 0; s < 2; ++s) {
            const int slot = tid + s * 512;               // 0..1023
            *(ushortx8*)(&w2s[slot * 8]) = *(const ushortx8*)(&W2F[slot * 8]);
        }
    }

    // stage pocket rows (pre-scaled): pure copy, 1 f32x4 per thread
    {
        const float* zpg = Z + (size_t)(NL_TOT + b * NPB + jt * JT_CHUNK) * H1DIM;
        const int row = tid >> 5;
        const int c4  = tid & 31;
        *(f32x4*)(&zp[row * ZP_STRIDE + c4 * 4]) =
            *(const f32x4*)(zpg + (size_t)row * H1DIM + c4 * 4);
    }

    // stage ALL 32 ligand rows (pre-scaled): pure copy, 2 f32x4 per thread
    {
        const float* zlg = Z + (size_t)(b * NLB) * H1DIM;
#pragma unroll
        for (int s = 0; s < 2; ++s) {
            const int u   = tid + s * 512;                // 0..1023
            const int row = u >> 5;
            const int c4  = u & 31;
            *(f32x4*)(&zl[row * H1DIM + c4 * 4]) =
                *(const f32x4*)(zlg + (size_t)row * H1DIM + c4 * 4);
        }
    }

    const int lane = tid & 63;
    const int widx = tid >> 6;                    // 0..7
    const int c    = lane & 15;
    const int q    = lane >> 4;

    // swapped-D layout: lane reg (nt, r) <-> h2 channel m = nt*16 + q*4 + r.
    // b2 scaled by -log2e (acc accumulates t2); W3 scaled by -ln2.
    f32x4 b2v[4], w3v[4];
#pragma unroll
    for (int nt = 0; nt < 4; ++nt) {
        f32x4 bv = *(const f32x4*)(b2 + nt * 16 + q * 4);
        f32x4 wv = *(const f32x4*)(W3 + nt * 16 + q * 4);
        b2v[nt] = bv * NEG_LOG2E;
        w3v[nt] = wv * NEG_LN2;
    }
    const float b3v = b3[0];

    __syncthreads();   // w2s + zp + zl visible; the ONLY barrier

    const float* prow = &zp[c * ZP_STRIDE];
    const unsigned short* wbase = &w2s[lane * 8];          // + chunk*512 ushorts

    // acc init = -log2e * b2 (per-channel, vectorized over r)
    f32x4 acc[4][4];                               // [atom][nt]
#pragma unroll
    for (int a = 0; a < 4; ++a)
#pragma unroll
        for (int nt = 0; nt < 4; ++nt) acc[a][nt] = b2v[nt];

    // wave's 4 atoms: widx*4 + a
    const float* lrow0 = &zl[(widx * 4) * H1DIM];

#pragma unroll
    for (int ks = 0; ks < 4; ++ks) {               // K = 128 = 4 x 32
        const int k0 = ks * 32 + q * 8;
        bf16x8 bfr[4];
#pragma unroll
        for (int nt = 0; nt < 4; ++nt)             // conflict-free ds_read_b128
            bfr[nt] = *(const bf16x8*)(wbase + (nt * 4 + ks) * 512);
        f32x4 pa = *(const f32x4*)(prow + k0);
        f32x4 pb = *(const f32x4*)(prow + k0 + 4);
#pragma unroll
        for (int a = 0; a < 4; ++a) {              // 4 atoms share bfr/pa/pb
            f32x4 la0 = *(const f32x4*)(lrow0 + a * H1DIM + k0);
            f32x4 la1 = *(const f32x4*)(lrow0 + a * H1DIM + k0 + 4);
            float hv[8];
#pragma unroll
            for (int j = 0; j < 4; ++j) {          // u = -log2e * silu(s)
                hv[j]     = silu_u(pa[j] + la0[j]);
                hv[4 + j] = silu_u(pb[j] + la1[j]);
            }
            bf16x8 af = pack8_rne(hv);
#pragma unroll
            for (int nt = 0; nt < 4; ++nt)         // SWAPPED: D^T, bitwise
                acc[a][nt] = __builtin_amdgcn_mfma_f32_16x16x32_bf16(bfr[nt], af, acc[a][nt], 0, 0, 0);
        }
    }

    // epilogue: lane holds t2 for channels m=nt*16+q*4+r, pocket c.
    // dot(silu_u(t2), w3v) per lane -> sum over q via shfl_xor 16/32.
#pragma unroll
    for (int at = 0; at < 4; ++at) {
        const f32x4* A = acc[at];
        float s0 = 0.f, s1 = 0.f, s2 = 0.f, s3 = 0.f;
#pragma unroll
        for (int nt = 0; nt < 4; ++nt) {           // u2 = -log2e*silu(h2pre)
            s0 += silu_u(A[nt][0]) * w3v[nt][0];
            s1 += silu_u(A[nt][1]) * w3v[nt][1];
            s2 += silu_u(A[nt][2]) * w3v[nt][2];
            s3 += silu_u(A[nt][3]) * w3v[nt][3];
        }
        float v = (s0 + s1) + (s2 + s3);           // per-lane partial (16 ch)
        v += __shfl_xor(v, 16);                    // q ^ 1
        v += __shfl_xor(v, 32);                    // q ^ 2 -> all 64 channels
        if (lane < 16) {
            const int e0 = (b * NLB + widx * 4 + at) * NPB + jt * JT_CHUNK;
            out[e0 + lane] = fmaxf(v + b3v, 0.0f); // 64B coalesced
        }
    }
}

// ---------------------------------------------------------------------------
extern "C" void kernel_launch(void* const* d_in, const int* in_sizes, int n_in,
                              void* d_out, int out_size, void* d_ws, size_t ws_size,
                              hipStream_t stream)
{
    const float* s_lig = (const float*)d_in[0];
    const float* s_poc = (const float*)d_in[1];
    const float* W1    = (const float*)d_in[4];
    const float* b1    = (const float*)d_in[5];
    const float* W2    = (const float*)d_in[6];
    const float* b2    = (const float*)d_in[7];
    const float* W3    = (const float*)d_in[8];
    const float* b3    = (const float*)d_in[9];

    float* Z = (float*)d_ws;                       // 12.58 MB (pre-scaled Z)
    unsigned short* W2F = (unsigned short*)(Z + (size_t)NROWS * H1DIM);  // +16 KB

    hipLaunchKernelGGL(proj_kernel, dim3(NROWS / 16 / 4 * 2), dim3(256), 0, stream,
                       s_lig, s_poc, W1, b1, W2, Z, W2F);
    hipLaunchKernelGGL(edge_kernel, dim3(EDGE_BLOCKS), dim3(512), 0, stream,
                       Z, W2F, b2, W3, b3, (float*)d_out);
}